// Round 12
// baseline (326.903 us; speedup 1.0000x reference)
//
#include <hip/hip_runtime.h>

typedef __attribute__((ext_vector_type(8))) short short8;
typedef __attribute__((ext_vector_type(4))) float f32x4;
typedef __attribute__((ext_vector_type(16))) float f32x16;
typedef unsigned int u32;
typedef __attribute__((ext_vector_type(4))) u32 u32x4;
typedef unsigned short u16;

#define DEV __device__ __forceinline__

DEV void async16(const void* g, void* l) {
  __builtin_amdgcn_global_load_lds((const __attribute__((address_space(1))) u32*)g,
                                   (__attribute__((address_space(3))) u32*)l, 16, 0, 0);
}

DEV u16 f2bf(float f) {
  u32 u = __builtin_bit_cast(u32, f);
  u32 r = (u + 0x7FFFu + ((u >> 16) & 1u)) >> 16;
  return (u16)r;
}
DEV float bf2f(u16 h) { return __builtin_bit_cast(float, (u32)h << 16); }

DEV u32 cvtpk(float lo, float hi) {  // packs {bf16(lo), bf16(hi)} -> u32 (lo in low16)
  u32 r;
  asm("v_cvt_pk_bf16_f32 %0, %1, %2" : "=v"(r) : "v"(lo), "v"(hi));
  return r;
}

// ---------------- fused cast f32 -> bf16 of x + 4 weights, + pack cos/sin float2 ----
__global__ void cast_all_kernel(const float* __restrict__ x, const float* __restrict__ wq,
                                const float* __restrict__ wk, const float* __restrict__ wv,
                                const float* __restrict__ wo, u16* __restrict__ out,
                                const float* __restrict__ cb, const float* __restrict__ sb,
                                float4* __restrict__ cs_ws) {
  constexpr int XN = 2097152;  // x float4 count (4096*2048/4)
  constexpr int WN = 1048576;  // each weight float4 count
  constexpr int TOT = XN + 4 * WN;
  constexpr int CSN = 32768;   // cos/sin float4 count (2048*64/4)
  int stride = gridDim.x * blockDim.x;
  for (int i = blockIdx.x * blockDim.x + threadIdx.x; i < TOT + CSN; i += stride) {
    if (i < TOT) {
      const float* src;
      int off;
      if (i < XN) {
        src = x; off = i;
      } else {
        int j = i - XN, wsel = j >> 20;
        const float* ws4[4] = {wq, wk, wv, wo};
        src = ws4[wsel]; off = j & (WN - 1);
      }
      float4 v = reinterpret_cast<const float4*>(src)[off];
      ushort4 o = make_ushort4(f2bf(v.x), f2bf(v.y), f2bf(v.z), f2bf(v.w));
      reinterpret_cast<ushort4*>(out)[i] = o;
    } else {
      int j = i - TOT;  // interleave cb/sb -> cs_ws[p] = {c, s} (float2 pairs)
      float4 c4 = reinterpret_cast<const float4*>(cb)[j];
      float4 s4 = reinterpret_cast<const float4*>(sb)[j];
      cs_ws[2 * j] = make_float4(c4.x, s4.x, c4.y, s4.y);
      cs_ws[2 * j + 1] = make_float4(c4.z, s4.z, c4.w, s4.w);
    }
  }
}

// ---------------- GEMM (m97 structure): C = A * B^T, 2-D XCD-mapped grid ----------
// 128x128 tile, BK=64, 4 waves, global_load_lds w16, XOR-swizzled LDS.
// Grid decode: each XCD owns a contiguous (16 M x 12 N) [MODE 0] or (16 M x 4 N)
// [MODE 1] tile region -> B/A panels stay in one XCD's L2.
// MODE 0: N=6144 fused QKV; epilogue RoPE on Q/K (pair via lane^1 shfl, f32; Q scaled
//   log2(e)/sqrt(128)); cos/sin from packed float2 table, batch-loaded. V transposed.
// MODE 1: N=2048, f32 row-major C (WO projection).
template <int MODE>
__global__ __launch_bounds__(256) void gemm_bt(const u16* __restrict__ A,
                                               const u16* __restrict__ Bw,
                                               void* __restrict__ C0,
                                               u16* __restrict__ C1,
                                               u16* __restrict__ C2,
                                               const float2* __restrict__ csp) {
  constexpr int K = 2048;
  __shared__ char sm[32768];  // A tile [128][64] @0, B tile [128][64] @16384, swizzled
  const int tid = threadIdx.x;
  const int lane = tid & 63;
  const int w = tid >> 6;
  const int bid = blockIdx.x;
  const int xcd = bid & 7, jj = bid >> 3;
  const int by = (xcd & 1) * 16 + (jj & 15);
  const int bx = (MODE == 0) ? ((xcd >> 1) * 12 + (jj >> 4))   // jj>>4 in [0,12)
                             : ((xcd >> 1) * 4 + (jj >> 4));   // jj>>4 in [0,4)
  const int row0 = by * 128, col0 = bx * 128;
  const int wr = (w >> 1) * 64, wc = (w & 1) * 64;
  f32x4 acc[4][4] = {};

  for (int k0 = 0; k0 < K; k0 += 64) {
    __syncthreads();
#pragma unroll
    for (int i = 0; i < 4; ++i) {
      int slot = tid + i * 256;
      int r = slot >> 3, s = slot & 7;
      int sl = s ^ (r & 7);
      async16(A + (size_t)(row0 + r) * K + (k0 + sl * 8), sm + slot * 16);
    }
#pragma unroll
    for (int i = 0; i < 4; ++i) {
      int slot = tid + i * 256;
      int r = slot >> 3, s = slot & 7;
      int sl = s ^ (r & 7);
      async16(Bw + (size_t)(col0 + r) * K + (k0 + sl * 8), sm + 16384 + slot * 16);
    }
    __syncthreads();
#pragma unroll
    for (int kk = 0; kk < 2; ++kk) {
      short8 af[4], bfr[4];
#pragma unroll
      for (int mi = 0; mi < 4; ++mi) {
        int r = wr + mi * 16 + (lane & 15);
        int ps = (kk * 4 + (lane >> 4)) ^ (r & 7);
        af[mi] = *reinterpret_cast<const short8*>(sm + r * 128 + ps * 16);
      }
#pragma unroll
      for (int ni = 0; ni < 4; ++ni) {
        int r = wc + ni * 16 + (lane & 15);
        int ps = (kk * 4 + (lane >> 4)) ^ (r & 7);
        bfr[ni] = *reinterpret_cast<const short8*>(sm + 16384 + r * 128 + ps * 16);
      }
#pragma unroll
      for (int mi = 0; mi < 4; ++mi)
#pragma unroll
        for (int ni = 0; ni < 4; ++ni)
          acc[mi][ni] = __builtin_amdgcn_mfma_f32_16x16x32_bf16(af[mi], bfr[ni], acc[mi][ni], 0, 0, 0);
    }
  }
  // ---- epilogue ----
  if constexpr (MODE == 0) {
    const int tsel = col0 >> 11;  // block-uniform: 0=Q, 1=K, 2=V
    if (tsel < 2) {
      const float sc = (tsel == 0) ? 0.127517436f : 1.0f;  // log2(e)/sqrt(128) on Q
      u16* dst = tsel ? C2 : (u16*)C0;
#pragma unroll
      for (int mi = 0; mi < 4; ++mi) {
        // batch-load 16 independent float2 (c,s) pairs -> pipelined
        float2 cs[4][4];
#pragma unroll
        for (int ni = 0; ni < 4; ++ni)
#pragma unroll
          for (int rr = 0; rr < 4; ++rr) {
            int gm = row0 + wr + mi * 16 + ((lane >> 4) << 2) + rr;
            int hd = wc + ni * 16 + (lane & 15);
            cs[ni][rr] = csp[((gm & 2047) << 6) + (hd >> 1)];
          }
#pragma unroll
        for (int ni = 0; ni < 4; ++ni)
#pragma unroll
          for (int rr = 0; rr < 4; ++rr) {
            int gm = row0 + wr + mi * 16 + ((lane >> 4) << 2) + rr;
            int hd = wc + ni * 16 + (lane & 15);
            int b = gm >> 11, s = gm & 2047;
            int hh = ((col0 & 2047) + wc + ni * 16) >> 7;  // head (block-uniform per ni)
            float v = acc[mi][ni][rr];
            float pv = __shfl_xor(v, 1, 64);
            float c = cs[ni][rr].x, sn = cs[ni][rr].y;
            float o = (hd & 1) ? (pv * sn + v * c) : (v * c - pv * sn);
            o *= sc;
            dst[(size_t)((b << 4) | hh) * 262144 + (s << 7) + (hd & 127)] = f2bf(o);
          }
      }
    } else {
#pragma unroll
      for (int mi = 0; mi < 4; ++mi)
#pragma unroll
        for (int ni = 0; ni < 4; ++ni)
#pragma unroll
          for (int rr = 0; rr < 4; ++rr) {
            int gm = row0 + wr + mi * 16 + ((lane >> 4) << 2) + rr;
            int gn = col0 + wc + ni * 16 + (lane & 15);
            int nn = gn & 2047;
            int b = gm >> 11, s = gm & 2047, h = nn >> 7, hd = nn & 127;
            C1[(size_t)((b << 4) | h) * 262144 + (hd << 11) + s] = f2bf(acc[mi][ni][rr]);
          }
    }
  } else {
#pragma unroll
    for (int mi = 0; mi < 4; ++mi)
#pragma unroll
      for (int ni = 0; ni < 4; ++ni)
#pragma unroll
        for (int rr = 0; rr < 4; ++rr) {
          int gm = row0 + wr + mi * 16 + ((lane >> 4) << 2) + rr;
          int gn = col0 + wc + ni * 16 + (lane & 15);
          ((float*)C0)[((size_t)gm << 11) + gn] = acc[mi][ni][rr];
        }
  }
}

// ---------------- causal flash attention (32x32 MFMA, swapped QK^T) ----
// 1024 blocks = 32 bh (XCD-clustered) x 32 q-tiles of 64 rows; 2 waves x 32 q-rows
// -> 4 independent blocks/CU (vs 2): smaller barrier groups, more staging streams.
// qt pairing (bid, bid+512): qt + qt' = 31 (balanced per-CU staged work).
// K-only LDS staging (dbuf 2x16KB); V read DIRECTLY from L2 into registers
// (per-bh V is XCD-resident: bh decode pins bh to one XCD; 4 bh x 1MB = L2 size).
// V loads issued BEFORE the K-stage (sched_barrier pins order) so the compiler's
// vmcnt for V does not drain the staging queue. Swapped QK^T -> in-register softmax
// (shfl_xor 32) + defer-max; P packed via cvt_pk + shfl_xor. PV computes O^T;
// epilogue transposes via LDS.
__global__ __launch_bounds__(128) void attn_kernel(const u16* __restrict__ q_ws,
                                                   const u16* __restrict__ k_ws,
                                                   const u16* __restrict__ vt_ws,
                                                   u16* __restrict__ attn_ws) {
  constexpr int S = 2048;
  constexpr float NEGBIG = -3.0e38f;  // finite mask value: exp2 -> 0, no inf arithmetic
  __shared__ char sm[32768];  // K dbuf: buf b @ b*16384, [64 rows][16 slots sw]
  const int tid = threadIdx.x, lane = tid & 63, w = tid >> 6;
  const int hi = lane >> 5, l31 = lane & 31;
  const int bid = blockIdx.x;
  const int qtr = bid >> 5;                           // 0..31
  const int qt = (qtr < 16) ? qtr : 47 - qtr;         // pair (bid,bid+512): qt+qt'=31
  const int bh = ((bid & 7) << 2) | ((bid >> 3) & 3); // same bh -> same XCD
  const int qr0 = qt * 64 + w * 32;
  const int ntile = qt + 1;  // staged kv tiles; ALL waves active on every tile

  const u16* qp = q_ws + (size_t)bh * S * 128;
  const u16* kp = k_ws + (size_t)bh * S * 128;
  const u16* vp = vt_ws + (size_t)bh * 128 * S;

  short8 qf[8];
  {
    const u16* qr = qp + (size_t)(qr0 + l31) * 128 + hi * 8;
#pragma unroll
    for (int ks = 0; ks < 8; ++ks) qf[ks] = *reinterpret_cast<const short8*>(qr + ks * 16);
  }
  f32x16 accO[4];
#pragma unroll
  for (int dc = 0; dc < 4; ++dc)
#pragma unroll
    for (int r = 0; r < 16; ++r) accO[dc][r] = 0.f;
  float m = -1e30f, l = 0.f;

  auto stageK = [&](int bufoff, int kv0) {
#pragma unroll
    for (int i = 0; i < 8; ++i) {  // K: 64 rows x 16 slots, 4-bit XOR swizzle
      int slot = tid + i * 128;
      int r = slot >> 4, s = slot & 15;
      async16(kp + (size_t)(kv0 + r) * 128 + ((s ^ (r & 15)) * 8), sm + bufoff + slot * 16);
    }
  };

  stageK(0, 0);
  __syncthreads();

  for (int t = 0; t < ntile; ++t) {
    const char* kb = sm + (t & 1) * 16384;
    // ---- issue V loads for tile t (global -> regs, L2-hit; no swizzle) ----
    short8 vreg[4][4];
#pragma unroll
    for (int ks = 0; ks < 4; ++ks)
#pragma unroll
      for (int dc = 0; dc < 4; ++dc)
        vreg[ks][dc] = *reinterpret_cast<const short8*>(
            vp + (size_t)(dc * 32 + l31) * S + t * 64 + (2 * ks + hi) * 8);
    __builtin_amdgcn_sched_barrier(0);  // keep V loads older than the K-stage below
    if (t + 1 < ntile) stageK(((t + 1) & 1) * 16384, (t + 1) * 64);

    // ---- QK^T swapped: sacc[jc][r] = S^T[j = 32jc+cr(r,hi)][q = qr0+l31] ----
    f32x16 sacc[2];
#pragma unroll
    for (int jc = 0; jc < 2; ++jc)
#pragma unroll
      for (int r = 0; r < 16; ++r) sacc[jc][r] = 0.f;
    __builtin_amdgcn_s_setprio(1);
#pragma unroll
    for (int jc = 0; jc < 2; ++jc) {
      const char* krp = kb + (jc * 32 + l31) * 256;
      const int sw = l31 & 15;
#pragma unroll
      for (int ks = 0; ks < 8; ++ks) {
        short8 kf = *reinterpret_cast<const short8*>(krp + (((2 * ks + hi) ^ sw) << 4));
        sacc[jc] = __builtin_amdgcn_mfma_f32_32x32x16_bf16(kf, qf[ks], sacc[jc], 0, 0, 0);
      }
    }
    __builtin_amdgcn_s_setprio(0);
    // ---- causal mask (only the diagonal tile t == qt) ----
    if (t == ntile - 1) {
#pragma unroll
      for (int jc = 0; jc < 2; ++jc) {
        int thr = qr0 + l31 - t * 64 - 32 * jc - 4 * hi;
#pragma unroll
        for (int r = 0; r < 16; ++r) {
          int c0 = (r & 3) + 8 * (r >> 2);
          if (c0 > thr) sacc[jc][r] = NEGBIG;
        }
      }
    }
    // ---- in-register online softmax; defer-max (T13) ----
    float pmA = NEGBIG, pmB = NEGBIG, pmC = NEGBIG, pmD = NEGBIG;
#pragma unroll
    for (int jc = 0; jc < 2; ++jc)
#pragma unroll
      for (int r = 0; r < 16; r += 4) {
        pmA = fmaxf(pmA, sacc[jc][r]);
        pmB = fmaxf(pmB, sacc[jc][r + 1]);
        pmC = fmaxf(pmC, sacc[jc][r + 2]);
        pmD = fmaxf(pmD, sacc[jc][r + 3]);
      }
    float pmax = fmaxf(fmaxf(pmA, pmB), fmaxf(pmC, pmD));
    pmax = fmaxf(pmax, __shfl_xor(pmax, 32, 64));
    if (!__all(pmax - m <= 8.0f)) {
      float mnew = fmaxf(m, pmax);
      float scl = exp2f(m - mnew);
      m = mnew;
      l *= scl;
#pragma unroll
      for (int dc = 0; dc < 4; ++dc)
#pragma unroll
        for (int r = 0; r < 16; ++r) accO[dc][r] *= scl;
    }
    float sA = 0.f, sB = 0.f, sC = 0.f, sD = 0.f;
#pragma unroll
    for (int jc = 0; jc < 2; ++jc)
#pragma unroll
      for (int r = 0; r < 16; r += 4) {
        float p0 = exp2f(sacc[jc][r] - m);
        float p1 = exp2f(sacc[jc][r + 1] - m);
        float p2 = exp2f(sacc[jc][r + 2] - m);
        float p3 = exp2f(sacc[jc][r + 3] - m);
        sacc[jc][r] = p0; sacc[jc][r + 1] = p1; sacc[jc][r + 2] = p2; sacc[jc][r + 3] = p3;
        sA += p0; sB += p1; sC += p2; sD += p3;
      }
    float ps = (sA + sB) + (sC + sD);
    ps += __shfl_xor(ps, 32, 64);
    l += ps;
    // ---- pack P -> bf16 B-fragments (cvt_pk + shfl_xor half-exchange) ----
    short8 pfrag[4];
#pragma unroll
    for (int ks = 0; ks < 4; ++ks) {
      const int jc = ks >> 1, u8 = (ks & 1) * 8;
      u32 wA = cvtpk(sacc[jc][u8 + 0], sacc[jc][u8 + 1]);
      u32 wB = cvtpk(sacc[jc][u8 + 2], sacc[jc][u8 + 3]);
      u32 wC = cvtpk(sacc[jc][u8 + 4], sacc[jc][u8 + 5]);
      u32 wD = cvtpk(sacc[jc][u8 + 6], sacc[jc][u8 + 7]);
      u32 qA = __shfl_xor(wA, 32, 64);
      u32 qB = __shfl_xor(wB, 32, 64);
      u32 qC = __shfl_xor(wC, 32, 64);
      u32 qD = __shfl_xor(wD, 32, 64);
      u32x4 t4;
      t4.x = hi ? qC : wA;
      t4.y = hi ? qD : wB;
      t4.z = hi ? wC : qA;
      t4.w = hi ? wD : qB;
      pfrag[ks] = __builtin_bit_cast(short8, t4);
    }
    // ---- PV from registers: accO[dc][r] = O^T[d = 32dc+cr(r,hi)][q = qr0+l31] ----
    __builtin_amdgcn_s_setprio(1);
#pragma unroll
    for (int ks = 0; ks < 4; ++ks)
#pragma unroll
      for (int dc = 0; dc < 4; ++dc)
        accO[dc] = __builtin_amdgcn_mfma_f32_32x32x16_bf16(vreg[ks][dc], pfrag[ks], accO[dc], 0, 0, 0);
    __builtin_amdgcn_s_setprio(0);
    __syncthreads();  // protects K dbuf reuse (stage t+1 landed; buf t&1 free)
  }

  // ---- epilogue: O^T -> LDS (swizzled) -> coalesced bf16 rows of attn_ws [B,S,D] ----
  const int b = bh >> 4, h = bh & 15;
  char* tb = sm + w * 8192;  // per-wave [32 q][128 d] bf16 tile
  float inv = (l > 0.f) ? 1.0f / l : 0.f;
#pragma unroll
  for (int dc = 0; dc < 4; ++dc)
#pragma unroll
    for (int r = 0; r < 16; ++r) {
      int d = dc * 32 + (r & 3) + 8 * (r >> 2) + 4 * hi;
      int byte = l31 * 256 + d * 2;
      *reinterpret_cast<u16*>(tb + (byte ^ ((l31 & 7) << 4))) = f2bf(accO[dc][r] * inv);
    }
  asm volatile("s_waitcnt lgkmcnt(0)" ::: "memory");
#pragma unroll
  for (int i = 0; i < 8; ++i) {
    int r = i * 4 + (lane >> 4);
    int s = lane & 15;
    f32x4 v = *reinterpret_cast<const f32x4*>(tb + r * 256 + ((s ^ (r & 7)) << 4));
    size_t addr = ((size_t)(b * 2048 + qr0 + r) << 11) + (h << 7) + s * 8;
    *reinterpret_cast<f32x4*>(attn_ws + addr) = v;
  }
}

extern "C" void kernel_launch(void* const* d_in, const int* in_sizes, int n_in,
                              void* d_out, int out_size, void* d_ws, size_t ws_size,
                              hipStream_t stream) {
  const float* x = (const float*)d_in[0];
  // d_in[1] = start_pos (0), d_in[4] = mask (causal) — handled analytically
  const float* cb = (const float*)d_in[2];
  const float* sb = (const float*)d_in[3];
  const float* wq = (const float*)d_in[5];
  const float* wk = (const float*)d_in[6];
  const float* wv = (const float*)d_in[7];
  const float* wo = (const float*)d_in[8];

  char* p = (char*)d_ws;
  u16* xb  = (u16*)p; p += (size_t)4096 * 2048 * 2;
  u16* wqb = (u16*)p; p += (size_t)2048 * 2048 * 2;  // wq,wk,wv,wo contiguous ->
  u16* wkb = (u16*)p; p += (size_t)2048 * 2048 * 2;  // fused QKV B = wqb[0..6144)
  u16* wvb = (u16*)p; p += (size_t)2048 * 2048 * 2;
  u16* wob = (u16*)p; p += (size_t)2048 * 2048 * 2;
  u16* q_ws = (u16*)p; p += (size_t)4096 * 2048 * 2;
  u16* k_ws = (u16*)p; p += (size_t)4096 * 2048 * 2;
  u16* vt_ws = (u16*)p; p += (size_t)4096 * 2048 * 2;
  float* cs_ws = (float*)p; p += (size_t)2048 * 64 * 2 * 4;  // packed {cos,sin} table
  u16* attn_ws = xb;  // xb is dead after the QKV projection; reuse it
  (void)wkb; (void)wvb;

  cast_all_kernel<<<3072, 256, 0, stream>>>(x, wq, wk, wv, wo, xb, cb, sb, (float4*)cs_ws);

  // MODE 0: C0=q_ws (tsel0), C1=vt_ws (tsel2), C2=k_ws (tsel1); RoPE fused
  gemm_bt<0><<<1536, 256, 0, stream>>>(xb, wqb, q_ws, vt_ws, k_ws, (const float2*)cs_ws);

  attn_kernel<<<1024, 128, 0, stream>>>(q_ws, k_ws, vt_ws, attn_ws);

  gemm_bt<1><<<512, 256, 0, stream>>>(attn_ws, wob, d_out, nullptr, nullptr, nullptr);
}

// Round 13
// 265.817 us; speedup vs baseline: 1.2298x; 1.2298x over previous
//
#include <hip/hip_runtime.h>

typedef __attribute__((ext_vector_type(8))) short short8;
typedef __attribute__((ext_vector_type(4))) float f32x4;
typedef __attribute__((ext_vector_type(16))) float f32x16;
typedef unsigned int u32;
typedef __attribute__((ext_vector_type(4))) u32 u32x4;
typedef unsigned short u16;

#define DEV __device__ __forceinline__

DEV void async16(const void* g, void* l) {
  __builtin_amdgcn_global_load_lds((const __attribute__((address_space(1))) u32*)g,
                                   (__attribute__((address_space(3))) u32*)l, 16, 0, 0);
}

DEV u16 f2bf(float f) {
  u32 u = __builtin_bit_cast(u32, f);
  u32 r = (u + 0x7FFFu + ((u >> 16) & 1u)) >> 16;
  return (u16)r;
}
DEV float bf2f(u16 h) { return __builtin_bit_cast(float, (u32)h << 16); }

DEV u32 cvtpk(float lo, float hi) {  // packs {bf16(lo), bf16(hi)} -> u32 (lo in low16)
  u32 r;
  asm("v_cvt_pk_bf16_f32 %0, %1, %2" : "=v"(r) : "v"(lo), "v"(hi));
  return r;
}

// ---------------- fused cast f32 -> bf16 of x + 4 weights, + pack cos/sin float2 ----
__global__ void cast_all_kernel(const float* __restrict__ x, const float* __restrict__ wq,
                                const float* __restrict__ wk, const float* __restrict__ wv,
                                const float* __restrict__ wo, u16* __restrict__ out,
                                const float* __restrict__ cb, const float* __restrict__ sb,
                                float4* __restrict__ cs_ws) {
  constexpr int XN = 2097152;  // x float4 count (4096*2048/4)
  constexpr int WN = 1048576;  // each weight float4 count
  constexpr int TOT = XN + 4 * WN;
  constexpr int CSN = 32768;   // cos/sin float4 count (2048*64/4)
  int stride = gridDim.x * blockDim.x;
  for (int i = blockIdx.x * blockDim.x + threadIdx.x; i < TOT + CSN; i += stride) {
    if (i < TOT) {
      const float* src;
      int off;
      if (i < XN) {
        src = x; off = i;
      } else {
        int j = i - XN, wsel = j >> 20;
        const float* ws4[4] = {wq, wk, wv, wo};
        src = ws4[wsel]; off = j & (WN - 1);
      }
      float4 v = reinterpret_cast<const float4*>(src)[off];
      ushort4 o = make_ushort4(f2bf(v.x), f2bf(v.y), f2bf(v.z), f2bf(v.w));
      reinterpret_cast<ushort4*>(out)[i] = o;
    } else {
      int j = i - TOT;  // interleave cb/sb -> cs_ws[p] = {c, s} (float2 pairs)
      float4 c4 = reinterpret_cast<const float4*>(cb)[j];
      float4 s4 = reinterpret_cast<const float4*>(sb)[j];
      cs_ws[2 * j] = make_float4(c4.x, s4.x, c4.y, s4.y);
      cs_ws[2 * j + 1] = make_float4(c4.z, s4.z, c4.w, s4.w);
    }
  }
}

// ---------------- GEMM (m97 structure, proven 34% MfmaUtil): C = A * B^T ----------
// 128x128 tile, BK=64, 4 waves, global_load_lds w16, XOR-swizzled LDS.
// MODE 0: N=6144 fused QKV; epilogue applies RoPE to Q/K (pair via lane^1 shfl, f32;
//   Q scaled log2(e)/sqrt(128)); cos/sin from packed float2 table, batch-loaded
//   16 pairs at a time (pipelined, no serial round-trips). Q/K -> [B,H,S,HD];
//   V -> [B,H,HD,S] transposed.
// MODE 1: N=2048, f32 row-major C (WO projection).
template <int MODE>
__global__ __launch_bounds__(256) void gemm_bt(const u16* __restrict__ A,
                                               const u16* __restrict__ Bw,
                                               void* __restrict__ C0,
                                               u16* __restrict__ C1,
                                               u16* __restrict__ C2,
                                               const float2* __restrict__ csp) {
  constexpr int K = 2048;
  __shared__ char sm[32768];  // A tile [128][64] @0, B tile [128][64] @16384, swizzled
  const int tid = threadIdx.x;
  const int lane = tid & 63;
  const int w = tid >> 6;
  const int by = blockIdx.x & 31;   // M/128 = 32
  const int bx = blockIdx.x >> 5;   // N/128 blocks (48 or 16)
  const int row0 = by * 128, col0 = bx * 128;
  const int wr = (w >> 1) * 64, wc = (w & 1) * 64;
  f32x4 acc[4][4] = {};

  for (int k0 = 0; k0 < K; k0 += 64) {
    __syncthreads();
#pragma unroll
    for (int i = 0; i < 4; ++i) {
      int slot = tid + i * 256;
      int r = slot >> 3, s = slot & 7;
      int sl = s ^ (r & 7);
      async16(A + (size_t)(row0 + r) * K + (k0 + sl * 8), sm + slot * 16);
    }
#pragma unroll
    for (int i = 0; i < 4; ++i) {
      int slot = tid + i * 256;
      int r = slot >> 3, s = slot & 7;
      int sl = s ^ (r & 7);
      async16(Bw + (size_t)(col0 + r) * K + (k0 + sl * 8), sm + 16384 + slot * 16);
    }
    __syncthreads();
#pragma unroll
    for (int kk = 0; kk < 2; ++kk) {
      short8 af[4], bfr[4];
#pragma unroll
      for (int mi = 0; mi < 4; ++mi) {
        int r = wr + mi * 16 + (lane & 15);
        int ps = (kk * 4 + (lane >> 4)) ^ (r & 7);
        af[mi] = *reinterpret_cast<const short8*>(sm + r * 128 + ps * 16);
      }
#pragma unroll
      for (int ni = 0; ni < 4; ++ni) {
        int r = wc + ni * 16 + (lane & 15);
        int ps = (kk * 4 + (lane >> 4)) ^ (r & 7);
        bfr[ni] = *reinterpret_cast<const short8*>(sm + 16384 + r * 128 + ps * 16);
      }
#pragma unroll
      for (int mi = 0; mi < 4; ++mi)
#pragma unroll
        for (int ni = 0; ni < 4; ++ni)
          acc[mi][ni] = __builtin_amdgcn_mfma_f32_16x16x32_bf16(af[mi], bfr[ni], acc[mi][ni], 0, 0, 0);
    }
  }
  // ---- epilogue ----
  if constexpr (MODE == 0) {
    const int tsel = col0 >> 11;  // block-uniform: 0=Q, 1=K, 2=V
    if (tsel < 2) {
      const float sc = (tsel == 0) ? 0.127517436f : 1.0f;  // log2(e)/sqrt(128) on Q
      u16* dst = tsel ? C2 : (u16*)C0;
#pragma unroll
      for (int mi = 0; mi < 4; ++mi) {
        // batch-load 16 independent float2 (c,s) pairs -> pipelined
        float2 cs[4][4];
#pragma unroll
        for (int ni = 0; ni < 4; ++ni)
#pragma unroll
          for (int rr = 0; rr < 4; ++rr) {
            int gm = row0 + wr + mi * 16 + ((lane >> 4) << 2) + rr;
            int hd = wc + ni * 16 + (lane & 15);
            cs[ni][rr] = csp[((gm & 2047) << 6) + (hd >> 1)];
          }
#pragma unroll
        for (int ni = 0; ni < 4; ++ni)
#pragma unroll
          for (int rr = 0; rr < 4; ++rr) {
            int gm = row0 + wr + mi * 16 + ((lane >> 4) << 2) + rr;
            int hd = wc + ni * 16 + (lane & 15);
            int b = gm >> 11, s = gm & 2047;
            int hh = ((col0 & 2047) + wc + ni * 16) >> 7;  // head (block-uniform per ni)
            float v = acc[mi][ni][rr];
            float pv = __shfl_xor(v, 1, 64);
            float c = cs[ni][rr].x, sn = cs[ni][rr].y;
            float o = (hd & 1) ? (pv * sn + v * c) : (v * c - pv * sn);
            o *= sc;
            dst[(size_t)((b << 4) | hh) * 262144 + (s << 7) + (hd & 127)] = f2bf(o);
          }
      }
    } else {
#pragma unroll
      for (int mi = 0; mi < 4; ++mi)
#pragma unroll
        for (int ni = 0; ni < 4; ++ni)
#pragma unroll
          for (int rr = 0; rr < 4; ++rr) {
            int gm = row0 + wr + mi * 16 + ((lane >> 4) << 2) + rr;
            int gn = col0 + wc + ni * 16 + (lane & 15);
            int nn = gn & 2047;
            int b = gm >> 11, s = gm & 2047, h = nn >> 7, hd = nn & 127;
            C1[(size_t)((b << 4) | h) * 262144 + (hd << 11) + s] = f2bf(acc[mi][ni][rr]);
          }
    }
  } else {
#pragma unroll
    for (int mi = 0; mi < 4; ++mi)
#pragma unroll
      for (int ni = 0; ni < 4; ++ni)
#pragma unroll
        for (int rr = 0; rr < 4; ++rr) {
          int gm = row0 + wr + mi * 16 + ((lane >> 4) << 2) + rr;
          int gn = col0 + wc + ni * 16 + (lane & 15);
          ((float*)C0)[((size_t)gm << 11) + gn] = acc[mi][ni][rr];
        }
  }
}

// ---------------- causal flash attention (32x32 MFMA, swapped QK^T) ----
// 512 blocks = 32 bh (XCD-clustered) x 16 q-tiles of 128 rows; 4 waves x 32 q-rows.
// qt decode pairs blocks (bid, bid+256) -> qt + qt' = 15 (balanced per-CU staged work).
// KVBLK=64 double-buffered (64KB LDS -> 2 blocks/CU). Swapped QK^T -> in-register
// softmax (shfl_xor 32 combine) + defer-max (T13); P packed via v_cvt_pk_bf16_f32 +
// shfl_xor half-exchange. PV computes O^T; epilogue transposes via LDS.
__global__ __launch_bounds__(256, 2) void attn_kernel(const u16* __restrict__ q_ws,
                                                      const u16* __restrict__ k_ws,
                                                      const u16* __restrict__ vt_ws,
                                                      u16* __restrict__ attn_ws) {
  constexpr int S = 2048;
  constexpr float NEGBIG = -3.0e38f;  // finite mask value: exp2 -> 0, no inf arithmetic
  __shared__ char sm[65536];
  const int tid = threadIdx.x, lane = tid & 63, w = tid >> 6;
  const int hi = lane >> 5, l31 = lane & 31;
  const int bid = blockIdx.x;
  const int qtr = bid >> 5;                           // 0..15
  const int qt = (qtr < 8) ? qtr : 23 - qtr;          // pair (bid,bid+256): qt+qt'=15
  const int bh = ((bid & 7) << 2) | ((bid >> 3) & 3); // same bh -> same XCD
  const int qr0 = qt * 128 + w * 32;
  const int ntile = 2 * qt + 2;       // staged kv tiles
  const int my_nt = (qr0 >> 6) + 1;   // wave-active kv tiles

  const u16* qp = q_ws + (size_t)bh * S * 128;
  const u16* kp = k_ws + (size_t)bh * S * 128;
  const u16* vp = vt_ws + (size_t)bh * 128 * S;

  short8 qf[8];
  {
    const u16* qr = qp + (size_t)(qr0 + l31) * 128 + hi * 8;
#pragma unroll
    for (int ks = 0; ks < 8; ++ks) qf[ks] = *reinterpret_cast<const short8*>(qr + ks * 16);
  }
  f32x16 accO[4];
#pragma unroll
  for (int dc = 0; dc < 4; ++dc)
#pragma unroll
    for (int r = 0; r < 16; ++r) accO[dc][r] = 0.f;
  float m = -1e30f, l = 0.f;

  auto stage = [&](int bufoff, int kv0) {
#pragma unroll
    for (int i = 0; i < 4; ++i) {  // K: 64 rows x 16 slots, 4-bit XOR swizzle
      int slot = tid + i * 256;
      int r = slot >> 4, s = slot & 15;
      async16(kp + (size_t)(kv0 + r) * 128 + ((s ^ (r & 15)) * 8), sm + bufoff + slot * 16);
    }
#pragma unroll
    for (int i = 0; i < 4; ++i) {  // Vt: 128 rows x 8 slots, 3-bit XOR swizzle
      int slot = tid + i * 256;
      int r = slot >> 3, s = slot & 7;
      async16(vp + (size_t)r * S + kv0 + ((s ^ (r & 7)) * 8), sm + bufoff + 16384 + slot * 16);
    }
  };

  stage(0, 0);
  __syncthreads();

  for (int t = 0; t < ntile; ++t) {
    const char* kb = sm + (t & 1) * 32768;
    const char* vb = kb + 16384;
    if (t + 1 < ntile) stage(((t + 1) & 1) * 32768, (t + 1) * 64);

    if (t < my_nt) {
      f32x16 sacc[2];
#pragma unroll
      for (int jc = 0; jc < 2; ++jc)
#pragma unroll
        for (int r = 0; r < 16; ++r) sacc[jc][r] = 0.f;
      __builtin_amdgcn_s_setprio(1);
#pragma unroll
      for (int jc = 0; jc < 2; ++jc) {
        const char* krp = kb + (jc * 32 + l31) * 256;
        const int sw = l31 & 15;
#pragma unroll
        for (int ks = 0; ks < 8; ++ks) {
          short8 kf = *reinterpret_cast<const short8*>(krp + (((2 * ks + hi) ^ sw) << 4));
          sacc[jc] = __builtin_amdgcn_mfma_f32_32x32x16_bf16(kf, qf[ks], sacc[jc], 0, 0, 0);
        }
      }
      __builtin_amdgcn_s_setprio(0);
      if (t == my_nt - 1) {
#pragma unroll
        for (int jc = 0; jc < 2; ++jc) {
          int thr = qr0 + l31 - t * 64 - 32 * jc - 4 * hi;
#pragma unroll
          for (int r = 0; r < 16; ++r) {
            int c0 = (r & 3) + 8 * (r >> 2);
            if (c0 > thr) sacc[jc][r] = NEGBIG;
          }
        }
      }
      float pmA = NEGBIG, pmB = NEGBIG, pmC = NEGBIG, pmD = NEGBIG;
#pragma unroll
      for (int jc = 0; jc < 2; ++jc)
#pragma unroll
        for (int r = 0; r < 16; r += 4) {
          pmA = fmaxf(pmA, sacc[jc][r]);
          pmB = fmaxf(pmB, sacc[jc][r + 1]);
          pmC = fmaxf(pmC, sacc[jc][r + 2]);
          pmD = fmaxf(pmD, sacc[jc][r + 3]);
        }
      float pmax = fmaxf(fmaxf(pmA, pmB), fmaxf(pmC, pmD));
      pmax = fmaxf(pmax, __shfl_xor(pmax, 32, 64));
      if (!__all(pmax - m <= 8.0f)) {
        float mnew = fmaxf(m, pmax);
        float scl = exp2f(m - mnew);
        m = mnew;
        l *= scl;
#pragma unroll
        for (int dc = 0; dc < 4; ++dc)
#pragma unroll
          for (int r = 0; r < 16; ++r) accO[dc][r] *= scl;
      }
      float sA = 0.f, sB = 0.f, sC = 0.f, sD = 0.f;
#pragma unroll
      for (int jc = 0; jc < 2; ++jc)
#pragma unroll
        for (int r = 0; r < 16; r += 4) {
          float p0 = exp2f(sacc[jc][r] - m);
          float p1 = exp2f(sacc[jc][r + 1] - m);
          float p2 = exp2f(sacc[jc][r + 2] - m);
          float p3 = exp2f(sacc[jc][r + 3] - m);
          sacc[jc][r] = p0; sacc[jc][r + 1] = p1; sacc[jc][r + 2] = p2; sacc[jc][r + 3] = p3;
          sA += p0; sB += p1; sC += p2; sD += p3;
        }
      float ps = (sA + sB) + (sC + sD);
      ps += __shfl_xor(ps, 32, 64);
      l += ps;
      short8 pfrag[4];
#pragma unroll
      for (int ks = 0; ks < 4; ++ks) {
        const int jc = ks >> 1, u8 = (ks & 1) * 8;
        u32 wA = cvtpk(sacc[jc][u8 + 0], sacc[jc][u8 + 1]);
        u32 wB = cvtpk(sacc[jc][u8 + 2], sacc[jc][u8 + 3]);
        u32 wC = cvtpk(sacc[jc][u8 + 4], sacc[jc][u8 + 5]);
        u32 wD = cvtpk(sacc[jc][u8 + 6], sacc[jc][u8 + 7]);
        u32 qA = __shfl_xor(wA, 32, 64);
        u32 qB = __shfl_xor(wB, 32, 64);
        u32 qC = __shfl_xor(wC, 32, 64);
        u32 qD = __shfl_xor(wD, 32, 64);
        u32x4 t4;
        t4.x = hi ? qC : wA;
        t4.y = hi ? qD : wB;
        t4.z = hi ? wC : qA;
        t4.w = hi ? wD : qB;
        pfrag[ks] = __builtin_bit_cast(short8, t4);
      }
      __builtin_amdgcn_s_setprio(1);
#pragma unroll
      for (int ks = 0; ks < 4; ++ks) {
#pragma unroll
        for (int dc = 0; dc < 4; ++dc) {
          const char* vrp = vb + (dc * 32 + l31) * 128;
          short8 vf = *reinterpret_cast<const short8*>(vrp + (((2 * ks + hi) ^ (l31 & 7)) << 4));
          accO[dc] = __builtin_amdgcn_mfma_f32_32x32x16_bf16(vf, pfrag[ks], accO[dc], 0, 0, 0);
        }
      }
      __builtin_amdgcn_s_setprio(0);
    }
    __syncthreads();
  }

  const int b = bh >> 4, h = bh & 15;
  char* tb = sm + w * 8192;
  float inv = (l > 0.f) ? 1.0f / l : 0.f;
#pragma unroll
  for (int dc = 0; dc < 4; ++dc)
#pragma unroll
    for (int r = 0; r < 16; ++r) {
      int d = dc * 32 + (r & 3) + 8 * (r >> 2) + 4 * hi;
      int byte = l31 * 256 + d * 2;
      *reinterpret_cast<u16*>(tb + (byte ^ ((l31 & 7) << 4))) = f2bf(accO[dc][r] * inv);
    }
  asm volatile("s_waitcnt lgkmcnt(0)" ::: "memory");
#pragma unroll
  for (int i = 0; i < 8; ++i) {
    int r = i * 4 + (lane >> 4);
    int s = lane & 15;
    f32x4 v = *reinterpret_cast<const f32x4*>(tb + r * 256 + ((s ^ (r & 7)) << 4));
    size_t addr = ((size_t)(b * 2048 + qr0 + r) << 11) + (h << 7) + s * 8;
    *reinterpret_cast<f32x4*>(attn_ws + addr) = v;
  }
}

extern "C" void kernel_launch(void* const* d_in, const int* in_sizes, int n_in,
                              void* d_out, int out_size, void* d_ws, size_t ws_size,
                              hipStream_t stream) {
  const float* x = (const float*)d_in[0];
  // d_in[1] = start_pos (0), d_in[4] = mask (causal) — handled analytically
  const float* cb = (const float*)d_in[2];
  const float* sb = (const float*)d_in[3];
  const float* wq = (const float*)d_in[5];
  const float* wk = (const float*)d_in[6];
  const float* wv = (const float*)d_in[7];
  const float* wo = (const float*)d_in[8];

  char* p = (char*)d_ws;
  u16* xb  = (u16*)p; p += (size_t)4096 * 2048 * 2;
  u16* wqb = (u16*)p; p += (size_t)2048 * 2048 * 2;  // wq,wk,wv,wo contiguous ->
  u16* wkb = (u16*)p; p += (size_t)2048 * 2048 * 2;  // fused QKV B = wqb[0..6144)
  u16* wvb = (u16*)p; p += (size_t)2048 * 2048 * 2;
  u16* wob = (u16*)p; p += (size_t)2048 * 2048 * 2;
  u16* q_ws = (u16*)p; p += (size_t)4096 * 2048 * 2;
  u16* k_ws = (u16*)p; p += (size_t)4096 * 2048 * 2;
  u16* vt_ws = (u16*)p; p += (size_t)4096 * 2048 * 2;
  float* cs_ws = (float*)p; p += (size_t)2048 * 64 * 2 * 4;  // packed {cos,sin} table
  u16* attn_ws = xb;  // xb is dead after the QKV projection; reuse it
  (void)wkb; (void)wvb;

  cast_all_kernel<<<3072, 256, 0, stream>>>(x, wq, wk, wv, wo, xb, cb, sb, (float4*)cs_ws);

  // MODE 0: C0=q_ws (tsel0), C1=vt_ws (tsel2), C2=k_ws (tsel1); RoPE fused
  gemm_bt<0><<<1536, 256, 0, stream>>>(xb, wqb, q_ws, vt_ws, k_ws, (const float2*)cs_ws);

  attn_kernel<<<512, 256, 0, stream>>>(q_ws, k_ws, vt_ws, attn_ws);

  gemm_bt<1><<<512, 256, 0, stream>>>(attn_ws, wob, d_out, nullptr, nullptr, nullptr);
}

// Round 14
// 263.939 us; speedup vs baseline: 1.2386x; 1.0071x over previous
//
#include <hip/hip_runtime.h>

typedef __attribute__((ext_vector_type(8))) short short8;
typedef __attribute__((ext_vector_type(4))) float f32x4;
typedef __attribute__((ext_vector_type(16))) float f32x16;
typedef unsigned int u32;
typedef __attribute__((ext_vector_type(4))) u32 u32x4;
typedef unsigned short u16;

#define DEV __device__ __forceinline__

DEV void async16(const void* g, void* l) {
  __builtin_amdgcn_global_load_lds((const __attribute__((address_space(1))) u32*)g,
                                   (__attribute__((address_space(3))) u32*)l, 16, 0, 0);
}

DEV u16 f2bf(float f) {
  u32 u = __builtin_bit_cast(u32, f);
  u32 r = (u + 0x7FFFu + ((u >> 16) & 1u)) >> 16;
  return (u16)r;
}
DEV float bf2f(u16 h) { return __builtin_bit_cast(float, (u32)h << 16); }

DEV u32 cvtpk(float lo, float hi) {  // packs {bf16(lo), bf16(hi)} -> u32 (lo in low16)
  u32 r;
  asm("v_cvt_pk_bf16_f32 %0, %1, %2" : "=v"(r) : "v"(lo), "v"(hi));
  return r;
}

// ---------------- fused cast f32 -> bf16 of x + 4 weights, + pack cos/sin float2 ----
__global__ void cast_all_kernel(const float* __restrict__ x, const float* __restrict__ wq,
                                const float* __restrict__ wk, const float* __restrict__ wv,
                                const float* __restrict__ wo, u16* __restrict__ out,
                                const float* __restrict__ cb, const float* __restrict__ sb,
                                float4* __restrict__ cs_ws) {
  constexpr int XN = 2097152;  // x float4 count (4096*2048/4)
  constexpr int WN = 1048576;  // each weight float4 count
  constexpr int TOT = XN + 4 * WN;
  constexpr int CSN = 32768;   // cos/sin float4 count (2048*64/4)
  int stride = gridDim.x * blockDim.x;
  for (int i = blockIdx.x * blockDim.x + threadIdx.x; i < TOT + CSN; i += stride) {
    if (i < TOT) {
      const float* src;
      int off;
      if (i < XN) {
        src = x; off = i;
      } else {
        int j = i - XN, wsel = j >> 20;
        const float* ws4[4] = {wq, wk, wv, wo};
        src = ws4[wsel]; off = j & (WN - 1);
      }
      float4 v = reinterpret_cast<const float4*>(src)[off];
      ushort4 o = make_ushort4(f2bf(v.x), f2bf(v.y), f2bf(v.z), f2bf(v.w));
      reinterpret_cast<ushort4*>(out)[i] = o;
    } else {
      int j = i - TOT;  // interleave cb/sb -> cs_ws[p] = {c, s} (float2 pairs)
      float4 c4 = reinterpret_cast<const float4*>(cb)[j];
      float4 s4 = reinterpret_cast<const float4*>(sb)[j];
      cs_ws[2 * j] = make_float4(c4.x, s4.x, c4.y, s4.y);
      cs_ws[2 * j + 1] = make_float4(c4.z, s4.z, c4.w, s4.w);
    }
  }
}

// ---------------- GEMM (m97 structure, proven 34% MfmaUtil): C = A * B^T ----------
// 128x128 tile, BK=64, 4 waves, global_load_lds w16, XOR-swizzled LDS.
// MODE 0: N=6144 fused QKV; epilogue applies RoPE to Q/K (pair via lane^1 shfl, f32;
//   Q scaled log2(e)/sqrt(128)); cos/sin from packed float2 table, batch-loaded.
//   Q/K -> [B,H,S,HD]; V -> [B,H,HD,S] via LDS transpose (coalesced 16B stores —
//   direct stores would hit 64 distinct 4KB-apart cachelines per wave-store).
// MODE 1: N=2048, f32 row-major C (WO projection).
template <int MODE>
__global__ __launch_bounds__(256) void gemm_bt(const u16* __restrict__ A,
                                               const u16* __restrict__ Bw,
                                               void* __restrict__ C0,
                                               u16* __restrict__ C1,
                                               u16* __restrict__ C2,
                                               const float2* __restrict__ csp) {
  constexpr int K = 2048;
  __shared__ char sm[32768];  // A tile [128][64] @0, B tile [128][64] @16384, swizzled
  const int tid = threadIdx.x;
  const int lane = tid & 63;
  const int w = tid >> 6;
  const int by = blockIdx.x & 31;   // M/128 = 32
  const int bx = blockIdx.x >> 5;   // N/128 blocks (48 or 16)
  const int row0 = by * 128, col0 = bx * 128;
  const int wr = (w >> 1) * 64, wc = (w & 1) * 64;
  f32x4 acc[4][4] = {};

  for (int k0 = 0; k0 < K; k0 += 64) {
    __syncthreads();
#pragma unroll
    for (int i = 0; i < 4; ++i) {
      int slot = tid + i * 256;
      int r = slot >> 3, s = slot & 7;
      int sl = s ^ (r & 7);
      async16(A + (size_t)(row0 + r) * K + (k0 + sl * 8), sm + slot * 16);
    }
#pragma unroll
    for (int i = 0; i < 4; ++i) {
      int slot = tid + i * 256;
      int r = slot >> 3, s = slot & 7;
      int sl = s ^ (r & 7);
      async16(Bw + (size_t)(col0 + r) * K + (k0 + sl * 8), sm + 16384 + slot * 16);
    }
    __syncthreads();
#pragma unroll
    for (int kk = 0; kk < 2; ++kk) {
      short8 af[4], bfr[4];
#pragma unroll
      for (int mi = 0; mi < 4; ++mi) {
        int r = wr + mi * 16 + (lane & 15);
        int ps = (kk * 4 + (lane >> 4)) ^ (r & 7);
        af[mi] = *reinterpret_cast<const short8*>(sm + r * 128 + ps * 16);
      }
#pragma unroll
      for (int ni = 0; ni < 4; ++ni) {
        int r = wc + ni * 16 + (lane & 15);
        int ps = (kk * 4 + (lane >> 4)) ^ (r & 7);
        bfr[ni] = *reinterpret_cast<const short8*>(sm + 16384 + r * 128 + ps * 16);
      }
#pragma unroll
      for (int mi = 0; mi < 4; ++mi)
#pragma unroll
        for (int ni = 0; ni < 4; ++ni)
          acc[mi][ni] = __builtin_amdgcn_mfma_f32_16x16x32_bf16(af[mi], bfr[ni], acc[mi][ni], 0, 0, 0);
    }
  }
  // ---- epilogue ----
  if constexpr (MODE == 0) {
    const int tsel = col0 >> 11;  // block-uniform: 0=Q, 1=K, 2=V
    if (tsel < 2) {
      const float sc = (tsel == 0) ? 0.127517436f : 1.0f;  // log2(e)/sqrt(128) on Q
      u16* dst = tsel ? C2 : (u16*)C0;
#pragma unroll
      for (int mi = 0; mi < 4; ++mi) {
        // batch-load 16 independent float2 (c,s) pairs -> pipelined
        float2 cs[4][4];
#pragma unroll
        for (int ni = 0; ni < 4; ++ni)
#pragma unroll
          for (int rr = 0; rr < 4; ++rr) {
            int gm = row0 + wr + mi * 16 + ((lane >> 4) << 2) + rr;
            int hd = wc + ni * 16 + (lane & 15);
            cs[ni][rr] = csp[((gm & 2047) << 6) + (hd >> 1)];
          }
#pragma unroll
        for (int ni = 0; ni < 4; ++ni)
#pragma unroll
          for (int rr = 0; rr < 4; ++rr) {
            int gm = row0 + wr + mi * 16 + ((lane >> 4) << 2) + rr;
            int hd = wc + ni * 16 + (lane & 15);
            int b = gm >> 11, s = gm & 2047;
            int hh = ((col0 & 2047) + wc + ni * 16) >> 7;  // head (block-uniform per ni)
            float v = acc[mi][ni][rr];
            float pv = __shfl_xor(v, 1, 64);
            float c = cs[ni][rr].x, sn = cs[ni][rr].y;
            float o = (hd & 1) ? (pv * sn + v * c) : (v * c - pv * sn);
            o *= sc;
            dst[(size_t)((b << 4) | hh) * 262144 + (s << 7) + (hd & 127)] = f2bf(o);
          }
      }
    } else {
      // V: transpose through LDS (32KB tile [hd][m], chunk-XOR swizzled) -> coalesced
      __syncthreads();  // all waves done with K-loop LDS reads
#pragma unroll
      for (int mi = 0; mi < 4; ++mi)
#pragma unroll
        for (int ni = 0; ni < 4; ++ni)
#pragma unroll
          for (int rr = 0; rr < 4; ++rr) {
            int ml = wr + mi * 16 + ((lane >> 4) << 2) + rr;  // 0..127 (s-local)
            int hl = wc + ni * 16 + (lane & 15);              // 0..127 (hd)
            int byte = hl * 256 + ((((ml >> 3) ^ (hl & 7))) << 4) + ((ml & 7) << 1);
            *reinterpret_cast<u16*>(sm + byte) = f2bf(acc[mi][ni][rr]);
          }
      __syncthreads();
      const int b = row0 >> 11;
      const int h = (col0 & 2047) >> 7;
      u16* vbase = C1 + (size_t)((b << 4) | h) * 262144 + (row0 & 2047);
#pragma unroll
      for (int it = 0; it < 8; ++it) {
        int idx = tid + it * 256;  // 0..2047 = 128 hd x 16 chunks
        int hl = idx >> 4, ch = idx & 15;
        int byte = hl * 256 + ((ch ^ (hl & 7)) << 4);
        u32x4 vv = *reinterpret_cast<const u32x4*>(sm + byte);
        *reinterpret_cast<u32x4*>(vbase + (size_t)hl * 2048 + ch * 8) = vv;
      }
    }
  } else {
#pragma unroll
    for (int mi = 0; mi < 4; ++mi)
#pragma unroll
      for (int ni = 0; ni < 4; ++ni)
#pragma unroll
        for (int rr = 0; rr < 4; ++rr) {
          int gm = row0 + wr + mi * 16 + ((lane >> 4) << 2) + rr;
          int gn = col0 + wc + ni * 16 + (lane & 15);
          ((float*)C0)[((size_t)gm << 11) + gn] = acc[mi][ni][rr];
        }
  }
}

// ---------------- causal flash attention (32x32 MFMA, swapped QK^T) ----
// 512 blocks = 32 bh (XCD-clustered) x 16 q-tiles of 128 rows; 4 waves x 32 q-rows.
// qt decode pairs blocks (bid, bid+256) -> qt + qt' = 15 (balanced per-CU staged work).
// KVBLK=64 double-buffered (64KB LDS -> 2 blocks/CU). Swapped QK^T -> in-register
// softmax (shfl_xor 32 combine) + defer-max (T13); P packed via v_cvt_pk_bf16_f32 +
// shfl_xor half-exchange. PV computes O^T; epilogue transposes via LDS.
__global__ __launch_bounds__(256, 2) void attn_kernel(const u16* __restrict__ q_ws,
                                                      const u16* __restrict__ k_ws,
                                                      const u16* __restrict__ vt_ws,
                                                      u16* __restrict__ attn_ws) {
  constexpr int S = 2048;
  constexpr float NEGBIG = -3.0e38f;  // finite mask value: exp2 -> 0, no inf arithmetic
  __shared__ char sm[65536];
  const int tid = threadIdx.x, lane = tid & 63, w = tid >> 6;
  const int hi = lane >> 5, l31 = lane & 31;
  const int bid = blockIdx.x;
  const int qtr = bid >> 5;                           // 0..15
  const int qt = (qtr < 8) ? qtr : 23 - qtr;          // pair (bid,bid+256): qt+qt'=15
  const int bh = ((bid & 7) << 2) | ((bid >> 3) & 3); // same bh -> same XCD
  const int qr0 = qt * 128 + w * 32;
  const int ntile = 2 * qt + 2;       // staged kv tiles
  const int my_nt = (qr0 >> 6) + 1;   // wave-active kv tiles

  const u16* qp = q_ws + (size_t)bh * S * 128;
  const u16* kp = k_ws + (size_t)bh * S * 128;
  const u16* vp = vt_ws + (size_t)bh * 128 * S;

  short8 qf[8];
  {
    const u16* qr = qp + (size_t)(qr0 + l31) * 128 + hi * 8;
#pragma unroll
    for (int ks = 0; ks < 8; ++ks) qf[ks] = *reinterpret_cast<const short8*>(qr + ks * 16);
  }
  f32x16 accO[4];
#pragma unroll
  for (int dc = 0; dc < 4; ++dc)
#pragma unroll
    for (int r = 0; r < 16; ++r) accO[dc][r] = 0.f;
  float m = -1e30f, l = 0.f;

  auto stage = [&](int bufoff, int kv0) {
#pragma unroll
    for (int i = 0; i < 4; ++i) {  // K: 64 rows x 16 slots, 4-bit XOR swizzle
      int slot = tid + i * 256;
      int r = slot >> 4, s = slot & 15;
      async16(kp + (size_t)(kv0 + r) * 128 + ((s ^ (r & 15)) * 8), sm + bufoff + slot * 16);
    }
#pragma unroll
    for (int i = 0; i < 4; ++i) {  // Vt: 128 rows x 8 slots, 3-bit XOR swizzle
      int slot = tid + i * 256;
      int r = slot >> 3, s = slot & 7;
      async16(vp + (size_t)r * S + kv0 + ((s ^ (r & 7)) * 8), sm + bufoff + 16384 + slot * 16);
    }
  };

  stage(0, 0);
  __syncthreads();

  for (int t = 0; t < ntile; ++t) {
    const char* kb = sm + (t & 1) * 32768;
    const char* vb = kb + 16384;
    if (t + 1 < ntile) stage(((t + 1) & 1) * 32768, (t + 1) * 64);

    if (t < my_nt) {
      f32x16 sacc[2];
#pragma unroll
      for (int jc = 0; jc < 2; ++jc)
#pragma unroll
        for (int r = 0; r < 16; ++r) sacc[jc][r] = 0.f;
      __builtin_amdgcn_s_setprio(1);
#pragma unroll
      for (int jc = 0; jc < 2; ++jc) {
        const char* krp = kb + (jc * 32 + l31) * 256;
        const int sw = l31 & 15;
#pragma unroll
        for (int ks = 0; ks < 8; ++ks) {
          short8 kf = *reinterpret_cast<const short8*>(krp + (((2 * ks + hi) ^ sw) << 4));
          sacc[jc] = __builtin_amdgcn_mfma_f32_32x32x16_bf16(kf, qf[ks], sacc[jc], 0, 0, 0);
        }
      }
      __builtin_amdgcn_s_setprio(0);
      if (t == my_nt - 1) {
#pragma unroll
        for (int jc = 0; jc < 2; ++jc) {
          int thr = qr0 + l31 - t * 64 - 32 * jc - 4 * hi;
#pragma unroll
          for (int r = 0; r < 16; ++r) {
            int c0 = (r & 3) + 8 * (r >> 2);
            if (c0 > thr) sacc[jc][r] = NEGBIG;
          }
        }
      }
      float pmA = NEGBIG, pmB = NEGBIG, pmC = NEGBIG, pmD = NEGBIG;
#pragma unroll
      for (int jc = 0; jc < 2; ++jc)
#pragma unroll
        for (int r = 0; r < 16; r += 4) {
          pmA = fmaxf(pmA, sacc[jc][r]);
          pmB = fmaxf(pmB, sacc[jc][r + 1]);
          pmC = fmaxf(pmC, sacc[jc][r + 2]);
          pmD = fmaxf(pmD, sacc[jc][r + 3]);
        }
      float pmax = fmaxf(fmaxf(pmA, pmB), fmaxf(pmC, pmD));
      pmax = fmaxf(pmax, __shfl_xor(pmax, 32, 64));
      if (!__all(pmax - m <= 8.0f)) {
        float mnew = fmaxf(m, pmax);
        float scl = exp2f(m - mnew);
        m = mnew;
        l *= scl;
#pragma unroll
        for (int dc = 0; dc < 4; ++dc)
#pragma unroll
          for (int r = 0; r < 16; ++r) accO[dc][r] *= scl;
      }
      float sA = 0.f, sB = 0.f, sC = 0.f, sD = 0.f;
#pragma unroll
      for (int jc = 0; jc < 2; ++jc)
#pragma unroll
        for (int r = 0; r < 16; r += 4) {
          float p0 = exp2f(sacc[jc][r] - m);
          float p1 = exp2f(sacc[jc][r + 1] - m);
          float p2 = exp2f(sacc[jc][r + 2] - m);
          float p3 = exp2f(sacc[jc][r + 3] - m);
          sacc[jc][r] = p0; sacc[jc][r + 1] = p1; sacc[jc][r + 2] = p2; sacc[jc][r + 3] = p3;
          sA += p0; sB += p1; sC += p2; sD += p3;
        }
      float ps = (sA + sB) + (sC + sD);
      ps += __shfl_xor(ps, 32, 64);
      l += ps;
      short8 pfrag[4];
#pragma unroll
      for (int ks = 0; ks < 4; ++ks) {
        const int jc = ks >> 1, u8 = (ks & 1) * 8;
        u32 wA = cvtpk(sacc[jc][u8 + 0], sacc[jc][u8 + 1]);
        u32 wB = cvtpk(sacc[jc][u8 + 2], sacc[jc][u8 + 3]);
        u32 wC = cvtpk(sacc[jc][u8 + 4], sacc[jc][u8 + 5]);
        u32 wD = cvtpk(sacc[jc][u8 + 6], sacc[jc][u8 + 7]);
        u32 qA = __shfl_xor(wA, 32, 64);
        u32 qB = __shfl_xor(wB, 32, 64);
        u32 qC = __shfl_xor(wC, 32, 64);
        u32 qD = __shfl_xor(wD, 32, 64);
        u32x4 t4;
        t4.x = hi ? qC : wA;
        t4.y = hi ? qD : wB;
        t4.z = hi ? wC : qA;
        t4.w = hi ? wD : qB;
        pfrag[ks] = __builtin_bit_cast(short8, t4);
      }
      __builtin_amdgcn_s_setprio(1);
#pragma unroll
      for (int ks = 0; ks < 4; ++ks) {
#pragma unroll
        for (int dc = 0; dc < 4; ++dc) {
          const char* vrp = vb + (dc * 32 + l31) * 128;
          short8 vf = *reinterpret_cast<const short8*>(vrp + (((2 * ks + hi) ^ (l31 & 7)) << 4));
          accO[dc] = __builtin_amdgcn_mfma_f32_32x32x16_bf16(vf, pfrag[ks], accO[dc], 0, 0, 0);
        }
      }
      __builtin_amdgcn_s_setprio(0);
    }
    __syncthreads();
  }

  const int b = bh >> 4, h = bh & 15;
  char* tb = sm + w * 8192;
  float inv = (l > 0.f) ? 1.0f / l : 0.f;
#pragma unroll
  for (int dc = 0; dc < 4; ++dc)
#pragma unroll
    for (int r = 0; r < 16; ++r) {
      int d = dc * 32 + (r & 3) + 8 * (r >> 2) + 4 * hi;
      int byte = l31 * 256 + d * 2;
      *reinterpret_cast<u16*>(tb + (byte ^ ((l31 & 7) << 4))) = f2bf(accO[dc][r] * inv);
    }
  asm volatile("s_waitcnt lgkmcnt(0)" ::: "memory");
#pragma unroll
  for (int i = 0; i < 8; ++i) {
    int r = i * 4 + (lane >> 4);
    int s = lane & 15;
    f32x4 v = *reinterpret_cast<const f32x4*>(tb + r * 256 + ((s ^ (r & 7)) << 4));
    size_t addr = ((size_t)(b * 2048 + qr0 + r) << 11) + (h << 7) + s * 8;
    *reinterpret_cast<f32x4*>(attn_ws + addr) = v;
  }
}

extern "C" void kernel_launch(void* const* d_in, const int* in_sizes, int n_in,
                              void* d_out, int out_size, void* d_ws, size_t ws_size,
                              hipStream_t stream) {
  const float* x = (const float*)d_in[0];
  // d_in[1] = start_pos (0), d_in[4] = mask (causal) — handled analytically
  const float* cb = (const float*)d_in[2];
  const float* sb = (const float*)d_in[3];
  const float* wq = (const float*)d_in[5];
  const float* wk = (const float*)d_in[6];
  const float* wv = (const float*)d_in[7];
  const float* wo = (const float*)d_in[8];

  char* p = (char*)d_ws;
  u16* xb  = (u16*)p; p += (size_t)4096 * 2048 * 2;
  u16* wqb = (u16*)p; p += (size_t)2048 * 2048 * 2;  // wq,wk,wv,wo contiguous ->
  u16* wkb = (u16*)p; p += (size_t)2048 * 2048 * 2;  // fused QKV B = wqb[0..6144)
  u16* wvb = (u16*)p; p += (size_t)2048 * 2048 * 2;
  u16* wob = (u16*)p; p += (size_t)2048 * 2048 * 2;
  u16* q_ws = (u16*)p; p += (size_t)4096 * 2048 * 2;
  u16* k_ws = (u16*)p; p += (size_t)4096 * 2048 * 2;
  u16* vt_ws = (u16*)p; p += (size_t)4096 * 2048 * 2;
  float* cs_ws = (float*)p; p += (size_t)2048 * 64 * 2 * 4;  // packed {cos,sin} table
  u16* attn_ws = xb;  // xb is dead after the QKV projection; reuse it
  (void)wkb; (void)wvb;

  cast_all_kernel<<<3072, 256, 0, stream>>>(x, wq, wk, wv, wo, xb, cb, sb, (float4*)cs_ws);

  // MODE 0: C0=q_ws (tsel0), C1=vt_ws (tsel2), C2=k_ws (tsel1); RoPE fused
  gemm_bt<0><<<1536, 256, 0, stream>>>(xb, wqb, q_ws, vt_ws, k_ws, (const float2*)cs_ws);

  attn_kernel<<<512, 256, 0, stream>>>(q_ws, k_ws, vt_ws, attn_ws);

  gemm_bt<1><<<512, 256, 0, stream>>>(attn_ws, wob, d_out, nullptr, nullptr, nullptr);
}